// Round 2
// baseline (230.585 us; speedup 1.0000x reference)
//
#include <hip/hip_runtime.h>
#include <utility>

#define NCH 23
#define CHUNK_V4 23      // 23 float4 = 92 elements = lcm(4,23) -> channels compile-time
#define CHUNK_ELEMS 92

// Class frequencies W from the reference.
constexpr float c_W[NCH] = {
    0.0012597430655963838f, 0.0004919313290455535f, 0.0021106513104319356f,
    0.0007678117365508301f, 0.004719881670572202f,  0.000372272357115554f,
    0.029090425620315438f,  0.010056339432617042f,  0.0034817436971298467f,
    0.0003057951504877765f, 0.003995280118329428f,  8.808229878180519e-05f,
    0.012070598793438699f,  0.016788818533845208f,  0.0017832510677901316f,
    0.0008758371973209686f, 0.0005933090691529143f, 0.0031992155689617922f,
    0.003212511010287348f,  0.0016685778863572154f, 0.0009356666832859684f,
    0.0010985358395240233f, 0.00103372056306194f
};
constexpr float NEG_LN2 = -0.69314718055994530942f;

// Weights pre-multiplied by -ln2 so the inner loop is: acc = fma(wn, log2(v), acc)
// (v <= 1 so log2(v) <= 0, wn < 0 -> positive loss contributions).
// fp32 op order matches reference: w0 = 1/(W+1); w1 = 1-w0; weights = 1/w0, 1/w1.
struct Tabs { float w0n[NCH]; float w1n[NCH]; };

constexpr Tabs make_tabs() {
    Tabs t{};
    for (int c = 0; c < NCH; ++c) {
        float w0 = 1.0f / (c_W[c] + 1.0f);   // _WEIGHT_0
        float w1 = 1.0f - w0;                // _WEIGHT_1
        t.w0n[c] = (1.0f / w0) * NEG_LN2;    // weight used when target == 0
        t.w1n[c] = (1.0f / w1) * NEG_LN2;    // weight used when target == 1
    }
    return t;
}

constexpr Tabs c_tabs = make_tabs();          // compile-time folded literals
__constant__ Tabs d_tabs = make_tabs();       // runtime-indexed copy (tail only)

__device__ __forceinline__ void elem(float xx, int lab, float w0n, float w1n,
                                     float& acc) {
    bool t  = lab > 0;
    float v = t ? xx : 1.0f - xx;
    float w = t ? w1n : w0n;
    acc = __builtin_fmaf(w, __log2f(v), acc);
}

template <int J>
__device__ __forceinline__ void do_vec4(const float4& xv, const int4& lv, float& acc) {
    elem(xv.x, lv.x, c_tabs.w0n[(4 * J + 0) % NCH], c_tabs.w1n[(4 * J + 0) % NCH], acc);
    elem(xv.y, lv.y, c_tabs.w0n[(4 * J + 1) % NCH], c_tabs.w1n[(4 * J + 1) % NCH], acc);
    elem(xv.z, lv.z, c_tabs.w0n[(4 * J + 2) % NCH], c_tabs.w1n[(4 * J + 2) % NCH], acc);
    elem(xv.w, lv.w, c_tabs.w0n[(4 * J + 3) % NCH], c_tabs.w1n[(4 * J + 3) % NCH], acc);
}

template <int... J>
__device__ __forceinline__ void do_chunk(const float4* __restrict__ xp,
                                         const int4* __restrict__ lp, float& acc,
                                         std::integer_sequence<int, J...>) {
    float4 xv[CHUNK_V4];
    int4   lv[CHUNK_V4];
    // Issue ALL 46 independent 16B loads before any compute (max MLP).
    ((xv[J] = xp[J]), ...);
    ((lv[J] = lp[J]), ...);
    (do_vec4<J>(xv[J], lv[J], acc), ...);
}

__global__ __launch_bounds__(256) void bce_reduce_kernel(
        const float* __restrict__ x, const int* __restrict__ labels,
        double* __restrict__ partial, unsigned n) {
    const unsigned nchunks = n / CHUNK_ELEMS;
    const unsigned t = blockIdx.x * blockDim.x + threadIdx.x;
    float acc = 0.0f;

    if (t < nchunks) {
        const float4* xp = (const float4*)x + (size_t)t * CHUNK_V4;
        const int4*   lp = (const int4*)labels + (size_t)t * CHUNK_V4;
        do_chunk(xp, lp, acc, std::make_integer_sequence<int, CHUNK_V4>{});
    }

    // Generic tail for n % 92 != 0 (no-op for n = 23e6).
    const unsigned tail = nchunks * CHUNK_ELEMS;
    const unsigned nthreads = gridDim.x * blockDim.x;
    for (unsigned i = tail + t; i < n; i += nthreads) {
        unsigned c = i % NCH;
        elem(x[i], labels[i], d_tabs.w0n[c], d_tabs.w1n[c], acc);
    }

    // Wave (64-lane) shuffle reduce, then LDS across the 4 waves.
    #pragma unroll
    for (int off = 32; off > 0; off >>= 1) acc += __shfl_down(acc, off, 64);
    __shared__ float s_part[4];
    const int wave = threadIdx.x >> 6;
    const int lane = threadIdx.x & 63;
    if (lane == 0) s_part[wave] = acc;
    __syncthreads();
    if (threadIdx.x == 0) {
        float s = s_part[0] + s_part[1] + s_part[2] + s_part[3];
        atomicAdd(partial, (double)s);
    }
}

__global__ void bce_finalize_kernel(const double* __restrict__ partial,
                                    float* __restrict__ out, unsigned n) {
    out[0] = (float)(partial[0] / (double)n);
}

extern "C" void kernel_launch(void* const* d_in, const int* in_sizes, int n_in,
                              void* d_out, int out_size, void* d_ws, size_t ws_size,
                              hipStream_t stream) {
    const float* x      = (const float*)d_in[0];
    const int*   labels = (const int*)d_in[1];
    float*       out    = (float*)d_out;
    double*      acc    = (double*)d_ws;
    unsigned n = (unsigned)in_sizes[0];  // B*C = 23,000,000

    hipMemsetAsync(acc, 0, sizeof(double), stream);

    const unsigned nchunks = n / CHUNK_ELEMS;          // 250,000
    const int block = 256;
    const int grid  = (int)((nchunks + block - 1) / block);  // 977
    bce_reduce_kernel<<<grid, block, 0, stream>>>(x, labels, acc, n);
    bce_finalize_kernel<<<1, 1, 0, stream>>>(acc, out, n);
}

// Round 3
// 197.917 us; speedup vs baseline: 1.1651x; 1.1651x over previous
//
#include <hip/hip_runtime.h>

#define NCH 23
#define U 4                 // vec4 loads per lane per wave-tile
#define TILE_V4 (64 * U)    // vec4s per wave-tile = 256 (1 tile = 1024 elements)

// Class frequencies W from the reference.
constexpr float c_W[NCH] = {
    0.0012597430655963838f, 0.0004919313290455535f, 0.0021106513104319356f,
    0.0007678117365508301f, 0.004719881670572202f,  0.000372272357115554f,
    0.029090425620315438f,  0.010056339432617042f,  0.0034817436971298467f,
    0.0003057951504877765f, 0.003995280118329428f,  8.808229878180519e-05f,
    0.012070598793438699f,  0.016788818533845208f,  0.0017832510677901316f,
    0.0008758371973209686f, 0.0005933090691529143f, 0.0031992155689617922f,
    0.003212511010287348f,  0.0016685778863572154f, 0.0009356666832859684f,
    0.0010985358395240233f, 0.00103372056306194f
};
constexpr float NEG_LN2 = -0.69314718055994530942f;

// Combined weight table, pre-multiplied by -ln2 so inner op is one fma with
// log2. w[c] = weight for target==0, w[23+c] = weight for target==1.
// fp32 op order matches reference: w0 = 1/(W+1); w1 = 1-w0; weights = 1/w0, 1/w1.
struct Tabs { float w[2 * NCH]; };
constexpr Tabs make_tabs() {
    Tabs t{};
    for (int c = 0; c < NCH; ++c) {
        float w0 = 1.0f / (c_W[c] + 1.0f);   // _WEIGHT_0
        float w1 = 1.0f - w0;                // _WEIGHT_1
        t.w[c]       = (1.0f / w0) * NEG_LN2;
        t.w[NCH + c] = (1.0f / w1) * NEG_LN2;
    }
    return t;
}
__constant__ Tabs d_tabs = make_tabs();

__device__ __forceinline__ unsigned wrap23(unsigned c) {
    return c >= NCH ? c - NCH : c;
}

__device__ __forceinline__ void elem(float xx, int lab, unsigned c,
                                     const float* s_wt, float& acc) {
    bool t  = lab > 0;
    float v = t ? xx : 1.0f - xx;
    float w = s_wt[c + (t ? NCH : 0u)];           // one ds_read_b32
    acc = __builtin_fmaf(w, __log2f(v), acc);     // wn * log2(v), wn = w * -ln2
}

__global__ __launch_bounds__(256) void bce_reduce_kernel(
        const float4* __restrict__ x4, const int4* __restrict__ l4,
        double* __restrict__ partial, unsigned n4 /* count of vec4s */) {
    __shared__ float s_wt[2 * NCH];
    if (threadIdx.x < 2 * NCH) s_wt[threadIdx.x] = d_tabs.w[threadIdx.x];
    __syncthreads();

    const unsigned gtid     = blockIdx.x * blockDim.x + threadIdx.x;
    const unsigned nthreads = gridDim.x * blockDim.x;
    const unsigned lane     = threadIdx.x & 63u;
    const unsigned wid      = gtid >> 6;
    const unsigned nwaves   = nthreads >> 6;
    const unsigned ntiles   = n4 / TILE_V4;

    float acc = 0.0f;

    for (unsigned T = wid; T < ntiles; T += nwaves) {
        const unsigned base = T * TILE_V4;  // vec4 index of tile start
        float4 xv[U];
        int4   lv[U];
        // 2U independent, wave-coalesced 16B loads — all in flight together.
        #pragma unroll
        for (int j = 0; j < U; ++j) xv[j] = x4[base + 64u * j + lane];
        #pragma unroll
        for (int j = 0; j < U; ++j) lv[j] = l4[base + 64u * j + lane];

        // channel of elem0 of load j: (4*(base + 64j + lane)) % 23
        //   = (12T + 4*lane + 3j) % 23  — one runtime mod per tile.
        const unsigned cb = (12u * T + 4u * lane) % NCH;
        #pragma unroll
        for (int j = 0; j < U; ++j) {
            unsigned c = wrap23(cb + (3u * j) % NCH);  // 3j%23 is compile-time
            elem(xv[j].x, lv[j].x, c, s_wt, acc); c = wrap23(c + 1);
            elem(xv[j].y, lv[j].y, c, s_wt, acc); c = wrap23(c + 1);
            elem(xv[j].z, lv[j].z, c, s_wt, acc); c = wrap23(c + 1);
            elem(xv[j].w, lv[j].w, c, s_wt, acc);
        }
    }

    // Tail over leftover vec4s (n4 % 256): runtime channel mod, few iterations.
    for (unsigned v = ntiles * TILE_V4 + gtid; v < n4; v += nthreads) {
        float4 xv = x4[v];
        int4   lv = l4[v];
        unsigned c = (4u * v) % NCH;
        elem(xv.x, lv.x, c, s_wt, acc); c = wrap23(c + 1);
        elem(xv.y, lv.y, c, s_wt, acc); c = wrap23(c + 1);
        elem(xv.z, lv.z, c, s_wt, acc); c = wrap23(c + 1);
        elem(xv.w, lv.w, c, s_wt, acc);
    }

    // Wave (64-lane) shuffle reduce, then LDS across the 4 waves.
    #pragma unroll
    for (int off = 32; off > 0; off >>= 1) acc += __shfl_down(acc, off, 64);
    __shared__ float s_part[4];
    const int wave = threadIdx.x >> 6;
    if ((threadIdx.x & 63) == 0) s_part[wave] = acc;
    __syncthreads();
    if (threadIdx.x == 0) {
        float s = s_part[0] + s_part[1] + s_part[2] + s_part[3];
        atomicAdd(partial, (double)s);
    }
}

__global__ void bce_finalize_kernel(const double* __restrict__ partial,
                                    float* __restrict__ out, unsigned n) {
    out[0] = (float)(partial[0] / (double)n);
}

extern "C" void kernel_launch(void* const* d_in, const int* in_sizes, int n_in,
                              void* d_out, int out_size, void* d_ws, size_t ws_size,
                              hipStream_t stream) {
    const float* x      = (const float*)d_in[0];
    const int*   labels = (const int*)d_in[1];
    float*       out    = (float*)d_out;
    double*      acc    = (double*)d_ws;
    unsigned n  = (unsigned)in_sizes[0];  // B*C = 23,000,000 (divisible by 4)
    unsigned n4 = n >> 2;

    hipMemsetAsync(acc, 0, sizeof(double), stream);

    const int block = 256;
    const int grid  = 1024;  // 4096 waves, ~5.5 tiles each; 16 waves/CU
    bce_reduce_kernel<<<grid, block, 0, stream>>>(
        (const float4*)x, (const int4*)labels, acc, n4);
    bce_finalize_kernel<<<1, 1, 0, stream>>>(acc, out, n);
}

// Round 4
// 197.186 us; speedup vs baseline: 1.1694x; 1.0037x over previous
//
#include <hip/hip_runtime.h>

#define NCH 23
#define U 2                 // vec4 loads per lane per wave-tile
#define TILE_V4 (64 * U)    // 128 vec4s per tile = 512 elements

// Class frequencies W from the reference.
constexpr float c_W[NCH] = {
    0.0012597430655963838f, 0.0004919313290455535f, 0.0021106513104319356f,
    0.0007678117365508301f, 0.004719881670572202f,  0.000372272357115554f,
    0.029090425620315438f,  0.010056339432617042f,  0.0034817436971298467f,
    0.0003057951504877765f, 0.003995280118329428f,  8.808229878180519e-05f,
    0.012070598793438699f,  0.016788818533845208f,  0.0017832510677901316f,
    0.0008758371973209686f, 0.0005933090691529143f, 0.0031992155689617922f,
    0.003212511010287348f,  0.0016685778863572154f, 0.0009356666832859684f,
    0.0010985358395240233f, 0.00103372056306194f
};
constexpr float NEG_LN2 = -0.69314718055994530942f;

// Combined weight table pre-multiplied by -ln2: w[c] for target==0, w[23+c]
// for target==1. fp32 op order matches reference.
struct Tabs { float w[2 * NCH]; };
constexpr Tabs make_tabs() {
    Tabs t{};
    for (int c = 0; c < NCH; ++c) {
        float w0 = 1.0f / (c_W[c] + 1.0f);   // _WEIGHT_0
        float w1 = 1.0f - w0;                // _WEIGHT_1
        t.w[c]       = (1.0f / w0) * NEG_LN2;
        t.w[NCH + c] = (1.0f / w1) * NEG_LN2;
    }
    return t;
}
__constant__ Tabs d_tabs = make_tabs();

__device__ __forceinline__ unsigned wrap23(unsigned c) {
    return c >= NCH ? c - NCH : c;
}

__device__ __forceinline__ void elem(float xx, int lab, unsigned c,
                                     const float* s_wt, float& acc) {
    bool t  = lab > 0;
    float v = t ? xx : 1.0f - xx;
    float w = s_wt[c + (t ? NCH : 0u)];           // one ds_read_b32
    acc = __builtin_fmaf(w, __log2f(v), acc);     // wn * log2(v), wn = w * -ln2
}

struct Buf { float4 xv[U]; int4 lv[U]; };

__device__ __forceinline__ void load_tile(const float4* __restrict__ x4,
                                          const int4* __restrict__ l4,
                                          unsigned T, unsigned lane, Buf& b) {
    const unsigned base = T * TILE_V4 + lane;
    #pragma unroll
    for (int j = 0; j < U; ++j) b.xv[j] = x4[base + 64u * j];
    #pragma unroll
    for (int j = 0; j < U; ++j) b.lv[j] = l4[base + 64u * j];
}

__device__ __forceinline__ void consume_tile(const Buf& b, unsigned T,
                                             unsigned lane, const float* s_wt,
                                             float& acc) {
    // channel of elem0 of load j: (4*(T*128 + 64j + lane)) % 23
    //   = (6T + 3j + 4*lane) % 23 — one runtime mod per tile.
    const unsigned cb = (6u * T + 4u * lane) % NCH;
    #pragma unroll
    for (int j = 0; j < U; ++j) {
        unsigned c = wrap23(cb + 3u * j);
        elem(b.xv[j].x, b.lv[j].x, c, s_wt, acc); c = wrap23(c + 1);
        elem(b.xv[j].y, b.lv[j].y, c, s_wt, acc); c = wrap23(c + 1);
        elem(b.xv[j].z, b.lv[j].z, c, s_wt, acc); c = wrap23(c + 1);
        elem(b.xv[j].w, b.lv[j].w, c, s_wt, acc);
    }
}

__global__ __launch_bounds__(256, 8) void bce_reduce_kernel(
        const float4* __restrict__ x4, const int4* __restrict__ l4,
        double* __restrict__ partial, unsigned n4 /* count of vec4s */) {
    __shared__ float s_wt[2 * NCH];
    if (threadIdx.x < 2 * NCH) s_wt[threadIdx.x] = d_tabs.w[threadIdx.x];
    __syncthreads();

    const unsigned gtid     = blockIdx.x * blockDim.x + threadIdx.x;
    const unsigned nthreads = gridDim.x * blockDim.x;
    const unsigned lane     = threadIdx.x & 63u;
    const unsigned wid      = gtid >> 6;
    const unsigned nwaves   = nthreads >> 6;
    const unsigned ntiles   = n4 / TILE_V4;

    float acc = 0.0f;

    // Double-buffered pipeline: next tile's 4 loads are always in flight
    // while the current tile is consumed.
    Buf b0, b1;
    unsigned T = wid;
    if (T < ntiles) {
        load_tile(x4, l4, T, lane, b0);
        while (true) {
            unsigned Tn = T + nwaves;
            if (Tn >= ntiles) { consume_tile(b0, T, lane, s_wt, acc); break; }
            load_tile(x4, l4, Tn, lane, b1);
            consume_tile(b0, T, lane, s_wt, acc);
            T = Tn;
            Tn = T + nwaves;
            if (Tn >= ntiles) { consume_tile(b1, T, lane, s_wt, acc); break; }
            load_tile(x4, l4, Tn, lane, b0);
            consume_tile(b1, T, lane, s_wt, acc);
            T = Tn;
        }
    }

    // Tail over leftover vec4s (n4 % 128).
    for (unsigned v = ntiles * TILE_V4 + gtid; v < n4; v += nthreads) {
        float4 xv = x4[v];
        int4   lv = l4[v];
        unsigned c = (4u * v) % NCH;
        elem(xv.x, lv.x, c, s_wt, acc); c = wrap23(c + 1);
        elem(xv.y, lv.y, c, s_wt, acc); c = wrap23(c + 1);
        elem(xv.z, lv.z, c, s_wt, acc); c = wrap23(c + 1);
        elem(xv.w, lv.w, c, s_wt, acc);
    }

    // Wave (64-lane) shuffle reduce, then LDS across the 4 waves.
    #pragma unroll
    for (int off = 32; off > 0; off >>= 1) acc += __shfl_down(acc, off, 64);
    __shared__ float s_part[4];
    const int wave = threadIdx.x >> 6;
    if ((threadIdx.x & 63) == 0) s_part[wave] = acc;
    __syncthreads();
    if (threadIdx.x == 0) {
        float s = s_part[0] + s_part[1] + s_part[2] + s_part[3];
        atomicAdd(partial, (double)s);
    }
}

__global__ void bce_finalize_kernel(const double* __restrict__ partial,
                                    float* __restrict__ out, unsigned n) {
    out[0] = (float)(partial[0] / (double)n);
}

extern "C" void kernel_launch(void* const* d_in, const int* in_sizes, int n_in,
                              void* d_out, int out_size, void* d_ws, size_t ws_size,
                              hipStream_t stream) {
    const float* x      = (const float*)d_in[0];
    const int*   labels = (const int*)d_in[1];
    float*       out    = (float*)d_out;
    double*      acc    = (double*)d_ws;
    unsigned n  = (unsigned)in_sizes[0];  // B*C = 23,000,000 (divisible by 4)
    unsigned n4 = n >> 2;

    hipMemsetAsync(acc, 0, sizeof(double), stream);

    const int block = 256;
    const int grid  = 2048;  // 8192 waves = 32 waves/CU (max occupancy)
    bce_reduce_kernel<<<grid, block, 0, stream>>>(
        (const float4*)x, (const int4*)labels, acc, n4);
    bce_finalize_kernel<<<1, 1, 0, stream>>>(acc, out, n);
}

// Round 6
// 192.750 us; speedup vs baseline: 1.1963x; 1.0230x over previous
//
#include <hip/hip_runtime.h>

#define NCH 23
#define U 4                 // vec4 loads per lane per wave-tile
#define TILE_V4 (64 * U)    // 256 vec4s per tile = 1024 elements

typedef float fvec4 __attribute__((ext_vector_type(4)));
typedef int   ivec4 __attribute__((ext_vector_type(4)));

// Class frequencies W from the reference.
constexpr float c_W[NCH] = {
    0.0012597430655963838f, 0.0004919313290455535f, 0.0021106513104319356f,
    0.0007678117365508301f, 0.004719881670572202f,  0.000372272357115554f,
    0.029090425620315438f,  0.010056339432617042f,  0.0034817436971298467f,
    0.0003057951504877765f, 0.003995280118329428f,  8.808229878180519e-05f,
    0.012070598793438699f,  0.016788818533845208f,  0.0017832510677901316f,
    0.0008758371973209686f, 0.0005933090691529143f, 0.0031992155689617922f,
    0.003212511010287348f,  0.0016685778863572154f, 0.0009356666832859684f,
    0.0010985358395240233f, 0.00103372056306194f
};
constexpr float NEG_LN2 = -0.69314718055994530942f;

// Combined weight table pre-multiplied by -ln2: w[c] for target==0, w[23+c]
// for target==1. fp32 op order matches reference.
struct Tabs { float w[2 * NCH]; };
constexpr Tabs make_tabs() {
    Tabs t{};
    for (int c = 0; c < NCH; ++c) {
        float w0 = 1.0f / (c_W[c] + 1.0f);   // _WEIGHT_0
        float w1 = 1.0f - w0;                // _WEIGHT_1
        t.w[c]       = (1.0f / w0) * NEG_LN2;
        t.w[NCH + c] = (1.0f / w1) * NEG_LN2;
    }
    return t;
}
__constant__ Tabs d_tabs = make_tabs();

__device__ __forceinline__ unsigned wrap23(unsigned c) {
    return c >= NCH ? c - NCH : c;
}

__device__ __forceinline__ void elem(float xx, int lab, unsigned c,
                                     const float* s_wt, float& acc) {
    bool t  = lab > 0;
    float v = t ? xx : 1.0f - xx;
    float w = s_wt[c + (t ? NCH : 0u)];           // one ds_read_b32
    acc = __builtin_fmaf(w, __log2f(v), acc);     // wn * log2(v), wn = w * -ln2
}

__global__ __launch_bounds__(256) void bce_reduce_kernel(
        const fvec4* __restrict__ x4, const ivec4* __restrict__ l4,
        double* __restrict__ partial, unsigned n4 /* count of vec4s */) {
    __shared__ float s_wt[2 * NCH];
    if (threadIdx.x < 2 * NCH) s_wt[threadIdx.x] = d_tabs.w[threadIdx.x];
    __syncthreads();

    const unsigned gtid     = blockIdx.x * blockDim.x + threadIdx.x;
    const unsigned nthreads = gridDim.x * blockDim.x;
    const unsigned lane     = threadIdx.x & 63u;
    const unsigned wid      = gtid >> 6;
    const unsigned nwaves   = nthreads >> 6;
    const unsigned ntiles   = n4 / TILE_V4;

    float acc = 0.0f;

    for (unsigned T = wid; T < ntiles; T += nwaves) {
        const unsigned base = T * TILE_V4 + lane;  // vec4 index for this lane
        fvec4 xv[U];
        ivec4 lv[U];
        // 2U independent, wave-coalesced, NONTEMPORAL 16B loads — read-once
        // streams, don't allocate in cache.
        #pragma unroll
        for (int j = 0; j < U; ++j)
            xv[j] = __builtin_nontemporal_load(&x4[base + 64u * j]);
        #pragma unroll
        for (int j = 0; j < U; ++j)
            lv[j] = __builtin_nontemporal_load(&l4[base + 64u * j]);

        // channel of elem0 of load j: (4*(T*256 + 64j + lane)) % 23
        //   = (12T + 3j + 4*lane) % 23 — one runtime mod per tile.
        const unsigned cb = (12u * T + 4u * lane) % NCH;
        #pragma unroll
        for (int j = 0; j < U; ++j) {
            unsigned c = wrap23(cb + (3u * j) % NCH);  // 3j%23 compile-time
            elem(xv[j].x, lv[j].x, c, s_wt, acc); c = wrap23(c + 1);
            elem(xv[j].y, lv[j].y, c, s_wt, acc); c = wrap23(c + 1);
            elem(xv[j].z, lv[j].z, c, s_wt, acc); c = wrap23(c + 1);
            elem(xv[j].w, lv[j].w, c, s_wt, acc);
        }
    }

    // Tail over leftover vec4s (n4 % 256).
    for (unsigned v = ntiles * TILE_V4 + gtid; v < n4; v += nthreads) {
        fvec4 xv = x4[v];
        ivec4 lv = l4[v];
        unsigned c = (4u * v) % NCH;
        elem(xv.x, lv.x, c, s_wt, acc); c = wrap23(c + 1);
        elem(xv.y, lv.y, c, s_wt, acc); c = wrap23(c + 1);
        elem(xv.z, lv.z, c, s_wt, acc); c = wrap23(c + 1);
        elem(xv.w, lv.w, c, s_wt, acc);
    }

    // Wave (64-lane) shuffle reduce, then LDS across the 4 waves.
    #pragma unroll
    for (int off = 32; off > 0; off >>= 1) acc += __shfl_down(acc, off, 64);
    __shared__ float s_part[4];
    const int wave = threadIdx.x >> 6;
    if ((threadIdx.x & 63) == 0) s_part[wave] = acc;
    __syncthreads();
    if (threadIdx.x == 0) {
        float s = s_part[0] + s_part[1] + s_part[2] + s_part[3];
        atomicAdd(partial, (double)s);
    }
}

__global__ void bce_finalize_kernel(const double* __restrict__ partial,
                                    float* __restrict__ out, unsigned n) {
    out[0] = (float)(partial[0] / (double)n);
}

extern "C" void kernel_launch(void* const* d_in, const int* in_sizes, int n_in,
                              void* d_out, int out_size, void* d_ws, size_t ws_size,
                              hipStream_t stream) {
    const float* x      = (const float*)d_in[0];
    const int*   labels = (const int*)d_in[1];
    float*       out    = (float*)d_out;
    double*      acc    = (double*)d_ws;
    unsigned n  = (unsigned)in_sizes[0];  // B*C = 23,000,000 (divisible by 4)
    unsigned n4 = n >> 2;

    (void)hipMemsetAsync(acc, 0, sizeof(double), stream);

    const int block = 256;
    const int grid  = 2048;  // 8192 waves = 32 waves/CU (max occupancy)
    bce_reduce_kernel<<<grid, block, 0, stream>>>(
        (const fvec4*)x, (const ivec4*)labels, acc, n4);
    bce_finalize_kernel<<<1, 1, 0, stream>>>(acc, out, n);
}

// Round 7
// 191.883 us; speedup vs baseline: 1.2017x; 1.0045x over previous
//
#include <hip/hip_runtime.h>

#define NCH 23
#define U 8                 // vec4 loads per lane per wave-tile
#define TILE_V4 (64 * U)    // 512 vec4s per tile = 2048 elements

typedef float fvec4 __attribute__((ext_vector_type(4)));
typedef int   ivec4 __attribute__((ext_vector_type(4)));

// Class frequencies W from the reference.
constexpr float c_W[NCH] = {
    0.0012597430655963838f, 0.0004919313290455535f, 0.0021106513104319356f,
    0.0007678117365508301f, 0.004719881670572202f,  0.000372272357115554f,
    0.029090425620315438f,  0.010056339432617042f,  0.0034817436971298467f,
    0.0003057951504877765f, 0.003995280118329428f,  8.808229878180519e-05f,
    0.012070598793438699f,  0.016788818533845208f,  0.0017832510677901316f,
    0.0008758371973209686f, 0.0005933090691529143f, 0.0031992155689617922f,
    0.003212511010287348f,  0.0016685778863572154f, 0.0009356666832859684f,
    0.0010985358395240233f, 0.00103372056306194f
};
constexpr float NEG_LN2 = -0.69314718055994530942f;

// Combined weight table pre-multiplied by -ln2: w[c] for target==0, w[23+c]
// for target==1. fp32 op order matches reference.
struct Tabs { float w[2 * NCH]; };
constexpr Tabs make_tabs() {
    Tabs t{};
    for (int c = 0; c < NCH; ++c) {
        float w0 = 1.0f / (c_W[c] + 1.0f);   // _WEIGHT_0
        float w1 = 1.0f - w0;                // _WEIGHT_1
        t.w[c]       = (1.0f / w0) * NEG_LN2;
        t.w[NCH + c] = (1.0f / w1) * NEG_LN2;
    }
    return t;
}
__constant__ Tabs d_tabs = make_tabs();

__device__ __forceinline__ unsigned wrap23(unsigned c) {
    return c >= NCH ? c - NCH : c;
}

__device__ __forceinline__ void elem(float xx, int lab, unsigned c,
                                     const float* s_wt, float& acc) {
    bool t  = lab > 0;
    float v = t ? xx : 1.0f - xx;
    float w = s_wt[c + (t ? NCH : 0u)];           // one ds_read_b32
    acc = __builtin_fmaf(w, __log2f(v), acc);     // wn * log2(v), wn = w * -ln2
}

__global__ __launch_bounds__(256) void bce_reduce_kernel(
        const fvec4* __restrict__ x4, const ivec4* __restrict__ l4,
        double* __restrict__ partial, unsigned n4 /* count of vec4s */) {
    __shared__ float s_wt[2 * NCH];
    if (threadIdx.x < 2 * NCH) s_wt[threadIdx.x] = d_tabs.w[threadIdx.x];
    __syncthreads();

    const unsigned gtid     = blockIdx.x * blockDim.x + threadIdx.x;
    const unsigned nthreads = gridDim.x * blockDim.x;
    const unsigned lane     = threadIdx.x & 63u;
    const unsigned wid      = gtid >> 6;
    const unsigned nwaves   = nthreads >> 6;
    const unsigned ntiles   = n4 / TILE_V4;

    float acc0 = 0.0f, acc1 = 0.0f;

    for (unsigned T = wid; T < ntiles; T += nwaves) {
        const fvec4* px = x4 + (size_t)T * TILE_V4 + lane;
        const ivec4* pl = l4 + (size_t)T * TILE_V4 + lane;
        fvec4 xv[U];
        ivec4 lv[U];
        // 2U = 16 independent, wave-coalesced, nontemporal 16B loads.
        #pragma unroll
        for (int j = 0; j < U; ++j)
            xv[j] = __builtin_nontemporal_load(px + 64u * j);
        #pragma unroll
        for (int j = 0; j < U; ++j)
            lv[j] = __builtin_nontemporal_load(pl + 64u * j);
        // Pin the load group ABOVE the compute group: forbid the scheduler
        // from sinking loads to their uses (R3/R4 showed it does: VGPR=32).
        __builtin_amdgcn_sched_barrier(0);

        // channel of elem0 of load j: (4*(T*512 + 64j + lane)) % 23
        //   = (T + 3j + 4*lane) % 23  (2048 = 89*23+1, 256 = 11*23+3).
        const unsigned cb = (T + 4u * lane) % NCH;
        #pragma unroll
        for (int j = 0; j < U; ++j) {
            unsigned c = wrap23(cb + (3u * j) % NCH);  // (3j)%23 compile-time
            float& a = (j & 1) ? acc1 : acc0;
            elem(xv[j].x, lv[j].x, c, s_wt, a); c = wrap23(c + 1);
            elem(xv[j].y, lv[j].y, c, s_wt, a); c = wrap23(c + 1);
            elem(xv[j].z, lv[j].z, c, s_wt, a); c = wrap23(c + 1);
            elem(xv[j].w, lv[j].w, c, s_wt, a);
        }
    }

    // Tail over leftover vec4s (n4 % 512).
    for (unsigned v = ntiles * TILE_V4 + gtid; v < n4; v += nthreads) {
        fvec4 xv = __builtin_nontemporal_load(x4 + v);
        ivec4 lv = __builtin_nontemporal_load(l4 + v);
        unsigned c = (4u * v) % NCH;
        elem(xv.x, lv.x, c, s_wt, acc0); c = wrap23(c + 1);
        elem(xv.y, lv.y, c, s_wt, acc0); c = wrap23(c + 1);
        elem(xv.z, lv.z, c, s_wt, acc0); c = wrap23(c + 1);
        elem(xv.w, lv.w, c, s_wt, acc0);
    }

    float acc = acc0 + acc1;

    // Wave (64-lane) shuffle reduce, then LDS across the 4 waves.
    #pragma unroll
    for (int off = 32; off > 0; off >>= 1) acc += __shfl_down(acc, off, 64);
    __shared__ float s_part[4];
    const int wave = threadIdx.x >> 6;
    if ((threadIdx.x & 63) == 0) s_part[wave] = acc;
    __syncthreads();
    if (threadIdx.x == 0) {
        float s = s_part[0] + s_part[1] + s_part[2] + s_part[3];
        atomicAdd(partial, (double)s);
    }
}

__global__ void bce_finalize_kernel(const double* __restrict__ partial,
                                    float* __restrict__ out, unsigned n) {
    out[0] = (float)(partial[0] / (double)n);
}

extern "C" void kernel_launch(void* const* d_in, const int* in_sizes, int n_in,
                              void* d_out, int out_size, void* d_ws, size_t ws_size,
                              hipStream_t stream) {
    const float* x      = (const float*)d_in[0];
    const int*   labels = (const int*)d_in[1];
    float*       out    = (float*)d_out;
    double*      acc    = (double*)d_ws;
    unsigned n  = (unsigned)in_sizes[0];  // B*C = 23,000,000 (divisible by 4)
    unsigned n4 = n >> 2;

    (void)hipMemsetAsync(acc, 0, sizeof(double), stream);

    const int block = 256;
    const int grid  = 2048;  // 8192 waves
    bce_reduce_kernel<<<grid, block, 0, stream>>>(
        (const fvec4*)x, (const ivec4*)labels, acc, n4);
    bce_finalize_kernel<<<1, 1, 0, stream>>>(acc, out, n);
}